// Round 5
// baseline (210.918 us; speedup 1.0000x reference)
//
#include <hip/hip_runtime.h>
#include <math.h>

#define EXTRA_COE 0.5f
#define ROWS_PER_BLOCK 4   // 4 waves of 64, one wave per row

typedef __attribute__((ext_vector_type(4))) float f32x4;

// R5: single-kernel version. R4's nt loads broke the 2.8 TB/s L2-alloc-path
// ceiling (kernel dropped out of top-5, i.e. <40 us, vs 72 us before).
// Remaining knob: remove the second launch + partials round-trip by
// accumulating the mean directly into d_out with one device-scope atomicAdd
// per block (d_out zeroed via hipMemsetAsync before the kernel).
__global__ __launch_bounds__(256) void st_loss_rows_1024(
    const float* __restrict__ ea, const float* __restrict__ ep,
    const float* __restrict__ en, const float* __restrict__ td,
    const int* __restrict__ bidx, float* __restrict__ out,
    float inv_b, int B)
{
    const int wave = threadIdx.x >> 6;
    const int lane = threadIdx.x & 63;
    const int row  = blockIdx.x * ROWS_PER_BLOCK + wave;

    float row_loss = 0.0f;
    if (row < B) {
        const size_t base = (size_t)row * 1024u;
        const f32x4* a4 = (const f32x4*)(ea + base);
        const f32x4* p4 = (const f32x4*)(ep + base);
        const f32x4* n4 = (const f32x4*)(en + base);

        f32x4 av[4], pv[4], nv[4];
        #pragma unroll
        for (int k = 0; k < 4; ++k) av[k] = __builtin_nontemporal_load(&a4[lane + 64 * k]);
        #pragma unroll
        for (int k = 0; k < 4; ++k) pv[k] = __builtin_nontemporal_load(&p4[lane + 64 * k]);
        #pragma unroll
        for (int k = 0; k < 4; ++k) nv[k] = __builtin_nontemporal_load(&n4[lane + 64 * k]);

        float s_ap = 0.0f, s_an = 0.0f;
        #pragma unroll
        for (int k = 0; k < 4; ++k) {
            f32x4 d = av[k] - pv[k];
            s_ap += d.x*d.x + d.y*d.y + d.z*d.z + d.w*d.w;
            d = av[k] - nv[k];
            s_an += d.x*d.x + d.y*d.y + d.z*d.z + d.w*d.w;
        }

        #pragma unroll
        for (int offx = 32; offx >= 1; offx >>= 1) {
            s_ap += __shfl_xor(s_ap, offx, 64);
            s_an += __shfl_xor(s_an, offx, 64);
        }
        if (lane == 0) {
            const float v_ap = expf(-sqrtf(s_ap));
            const float v_an = expf(-sqrtf(s_an));
            const int idx = bidx[row];
            const float d0 = td[2 * idx + 0] * EXTRA_COE;
            const float d1 = td[2 * idx + 1] * EXTRA_COE;
            const float D_ap = expf(-d0);
            const float D_an = expf(-d1);
            float l = (D_ap - v_ap) * (D_ap - v_ap)
                    + (D_an - v_an) * (D_an - v_an);
            if (D_ap > D_an) {
                float m = v_an - v_ap;
                m = m > 0.0f ? m : 0.0f;
                l += m * m;
            }
            row_loss = l;
        }
    }

    __shared__ float sm[ROWS_PER_BLOCK];
    if (lane == 0) sm[wave] = row_loss;
    __syncthreads();
    if (threadIdx.x == 0) {
        float s = 0.0f;
        #pragma unroll
        for (int w = 0; w < ROWS_PER_BLOCK; ++w) s += sm[w];
        atomicAdd(out, s * inv_b);   // device-scope by default on gfx950
    }
}

// Generic-D fallback (nt loads, same atomic epilogue).
__global__ __launch_bounds__(256) void st_loss_rows_gen(
    const float* __restrict__ ea, const float* __restrict__ ep,
    const float* __restrict__ en, const float* __restrict__ td,
    const int* __restrict__ bidx, float* __restrict__ out,
    float inv_b, int B, int D)
{
    const int wave = threadIdx.x >> 6;
    const int lane = threadIdx.x & 63;
    const int row  = blockIdx.x * ROWS_PER_BLOCK + wave;

    float row_loss = 0.0f;
    if (row < B) {
        const size_t base = (size_t)row * (size_t)D;
        const f32x4* a4 = (const f32x4*)(ea + base);
        const f32x4* p4 = (const f32x4*)(ep + base);
        const f32x4* n4 = (const f32x4*)(en + base);
        const int nvec = D >> 2;

        float s_ap = 0.0f, s_an = 0.0f;
        for (int j = lane; j < nvec; j += 64) {
            f32x4 av = __builtin_nontemporal_load(&a4[j]);
            f32x4 pv = __builtin_nontemporal_load(&p4[j]);
            f32x4 nv = __builtin_nontemporal_load(&n4[j]);
            f32x4 d = av - pv;
            s_ap += d.x*d.x + d.y*d.y + d.z*d.z + d.w*d.w;
            d = av - nv;
            s_an += d.x*d.x + d.y*d.y + d.z*d.z + d.w*d.w;
        }
        #pragma unroll
        for (int offx = 32; offx >= 1; offx >>= 1) {
            s_ap += __shfl_xor(s_ap, offx, 64);
            s_an += __shfl_xor(s_an, offx, 64);
        }
        if (lane == 0) {
            const float v_ap = expf(-sqrtf(s_ap));
            const float v_an = expf(-sqrtf(s_an));
            const int idx = bidx[row];
            const float d0 = td[2 * idx + 0] * EXTRA_COE;
            const float d1 = td[2 * idx + 1] * EXTRA_COE;
            const float D_ap = expf(-d0);
            const float D_an = expf(-d1);
            float l = (D_ap - v_ap) * (D_ap - v_ap)
                    + (D_an - v_an) * (D_an - v_an);
            if (D_ap > D_an) {
                float m = v_an - v_ap;
                m = m > 0.0f ? m : 0.0f;
                l += m * m;
            }
            row_loss = l;
        }
    }

    __shared__ float sm[ROWS_PER_BLOCK];
    if (lane == 0) sm[wave] = row_loss;
    __syncthreads();
    if (threadIdx.x == 0) {
        float s = 0.0f;
        #pragma unroll
        for (int w = 0; w < ROWS_PER_BLOCK; ++w) s += sm[w];
        atomicAdd(out, s * inv_b);
    }
}

extern "C" void kernel_launch(void* const* d_in, const int* in_sizes, int n_in,
                              void* d_out, int out_size, void* d_ws, size_t ws_size,
                              hipStream_t stream) {
    const float* ea   = (const float*)d_in[0];
    const float* ep   = (const float*)d_in[1];
    const float* en   = (const float*)d_in[2];
    const float* td   = (const float*)d_in[3];
    const int*   bidx = (const int*)d_in[4];
    float* out = (float*)d_out;

    const int B = in_sizes[4];                 // 16384 rows
    const int D = in_sizes[0] / B;             // 1024
    const int n_blocks = (B + ROWS_PER_BLOCK - 1) / ROWS_PER_BLOCK;
    const float inv_b = 1.0f / (float)B;

    // d_out is re-poisoned to 0xAA before every timed launch; zero it for
    // the atomic accumulation. hipMemsetAsync is graph-capture-safe.
    hipMemsetAsync(out, 0, sizeof(float), stream);

    if (D == 1024) {
        st_loss_rows_1024<<<n_blocks, 256, 0, stream>>>(ea, ep, en, td, bidx,
                                                        out, inv_b, B);
    } else {
        st_loss_rows_gen<<<n_blocks, 256, 0, stream>>>(ea, ep, en, td, bidx,
                                                       out, inv_b, B, D);
    }
}

// Round 6
// 183.054 us; speedup vs baseline: 1.1522x; 1.1522x over previous
//
#include <hip/hip_runtime.h>
#include <math.h>

#define EXTRA_COE 0.5f
#define ROWS_PER_BLOCK 4   // 4 waves of 64, one wave per row

typedef __attribute__((ext_vector_type(4))) float f32x4;

// R6 = revert to R4 (best measured: 183.5 us total, kernel <40 us).
// R5's single-atomic-address epilogue cost +26 us (4096 same-address
// device atomics serialize at one L2 slice) -- two-kernel structure wins.
// Main kernel: one wave per row, 12 nontemporal global_load_dwordx4
// (L2-bypass for zero-reuse streams; this broke R1-R3's 2.8 TB/s
// L2-allocation-path ceiling), wave butterfly reduce, per-block partial.
__global__ __launch_bounds__(256) void st_loss_rows_1024(
    const float* __restrict__ ea, const float* __restrict__ ep,
    const float* __restrict__ en, const float* __restrict__ td,
    const int* __restrict__ bidx, float* __restrict__ partial, int B)
{
    const int wave = threadIdx.x >> 6;
    const int lane = threadIdx.x & 63;
    const int row  = blockIdx.x * ROWS_PER_BLOCK + wave;

    float row_loss = 0.0f;
    if (row < B) {
        const size_t base = (size_t)row * 1024u;
        const f32x4* a4 = (const f32x4*)(ea + base);
        const f32x4* p4 = (const f32x4*)(ep + base);
        const f32x4* n4 = (const f32x4*)(en + base);

        f32x4 av[4], pv[4], nv[4];
        #pragma unroll
        for (int k = 0; k < 4; ++k) av[k] = __builtin_nontemporal_load(&a4[lane + 64 * k]);
        #pragma unroll
        for (int k = 0; k < 4; ++k) pv[k] = __builtin_nontemporal_load(&p4[lane + 64 * k]);
        #pragma unroll
        for (int k = 0; k < 4; ++k) nv[k] = __builtin_nontemporal_load(&n4[lane + 64 * k]);

        float s_ap = 0.0f, s_an = 0.0f;
        #pragma unroll
        for (int k = 0; k < 4; ++k) {
            f32x4 d = av[k] - pv[k];
            s_ap += d.x*d.x + d.y*d.y + d.z*d.z + d.w*d.w;
            d = av[k] - nv[k];
            s_an += d.x*d.x + d.y*d.y + d.z*d.z + d.w*d.w;
        }

        #pragma unroll
        for (int offx = 32; offx >= 1; offx >>= 1) {
            s_ap += __shfl_xor(s_ap, offx, 64);
            s_an += __shfl_xor(s_an, offx, 64);
        }
        if (lane == 0) {
            const float v_ap = expf(-sqrtf(s_ap));
            const float v_an = expf(-sqrtf(s_an));
            const int idx = bidx[row];
            const float d0 = td[2 * idx + 0] * EXTRA_COE;
            const float d1 = td[2 * idx + 1] * EXTRA_COE;
            const float D_ap = expf(-d0);
            const float D_an = expf(-d1);
            float l = (D_ap - v_ap) * (D_ap - v_ap)
                    + (D_an - v_an) * (D_an - v_an);
            if (D_ap > D_an) {
                float m = v_an - v_ap;
                m = m > 0.0f ? m : 0.0f;
                l += m * m;
            }
            row_loss = l;
        }
    }

    __shared__ float sm[ROWS_PER_BLOCK];
    if (lane == 0) sm[wave] = row_loss;
    __syncthreads();
    if (threadIdx.x == 0) {
        float s = 0.0f;
        #pragma unroll
        for (int w = 0; w < ROWS_PER_BLOCK; ++w) s += sm[w];
        partial[blockIdx.x] = s;
    }
}

// Generic-D fallback (nt loads).
__global__ __launch_bounds__(256) void st_loss_rows_gen(
    const float* __restrict__ ea, const float* __restrict__ ep,
    const float* __restrict__ en, const float* __restrict__ td,
    const int* __restrict__ bidx, float* __restrict__ partial,
    int B, int D)
{
    const int wave = threadIdx.x >> 6;
    const int lane = threadIdx.x & 63;
    const int row  = blockIdx.x * ROWS_PER_BLOCK + wave;

    float row_loss = 0.0f;
    if (row < B) {
        const size_t base = (size_t)row * (size_t)D;
        const f32x4* a4 = (const f32x4*)(ea + base);
        const f32x4* p4 = (const f32x4*)(ep + base);
        const f32x4* n4 = (const f32x4*)(en + base);
        const int nvec = D >> 2;

        float s_ap = 0.0f, s_an = 0.0f;
        for (int j = lane; j < nvec; j += 64) {
            f32x4 av = __builtin_nontemporal_load(&a4[j]);
            f32x4 pv = __builtin_nontemporal_load(&p4[j]);
            f32x4 nv = __builtin_nontemporal_load(&n4[j]);
            f32x4 d = av - pv;
            s_ap += d.x*d.x + d.y*d.y + d.z*d.z + d.w*d.w;
            d = av - nv;
            s_an += d.x*d.x + d.y*d.y + d.z*d.z + d.w*d.w;
        }
        #pragma unroll
        for (int offx = 32; offx >= 1; offx >>= 1) {
            s_ap += __shfl_xor(s_ap, offx, 64);
            s_an += __shfl_xor(s_an, offx, 64);
        }
        if (lane == 0) {
            const float v_ap = expf(-sqrtf(s_ap));
            const float v_an = expf(-sqrtf(s_an));
            const int idx = bidx[row];
            const float d0 = td[2 * idx + 0] * EXTRA_COE;
            const float d1 = td[2 * idx + 1] * EXTRA_COE;
            const float D_ap = expf(-d0);
            const float D_an = expf(-d1);
            float l = (D_ap - v_ap) * (D_ap - v_ap)
                    + (D_an - v_an) * (D_an - v_an);
            if (D_ap > D_an) {
                float m = v_an - v_ap;
                m = m > 0.0f ? m : 0.0f;
                l += m * m;
            }
            row_loss = l;
        }
    }

    __shared__ float sm[ROWS_PER_BLOCK];
    if (lane == 0) sm[wave] = row_loss;
    __syncthreads();
    if (threadIdx.x == 0) {
        float s = 0.0f;
        #pragma unroll
        for (int w = 0; w < ROWS_PER_BLOCK; ++w) s += sm[w];
        partial[blockIdx.x] = s;
    }
}

__global__ __launch_bounds__(256) void st_loss_final(
    const float* __restrict__ partial, int n_partial,
    float* __restrict__ out, float inv_b)
{
    float s = 0.0f;
    for (int i = threadIdx.x; i < n_partial; i += 256) s += partial[i];
    #pragma unroll
    for (int offx = 32; offx >= 1; offx >>= 1) s += __shfl_xor(s, offx, 64);
    __shared__ float sm[4];
    if ((threadIdx.x & 63) == 0) sm[threadIdx.x >> 6] = s;
    __syncthreads();
    if (threadIdx.x == 0) out[0] = (sm[0] + sm[1] + sm[2] + sm[3]) * inv_b;
}

extern "C" void kernel_launch(void* const* d_in, const int* in_sizes, int n_in,
                              void* d_out, int out_size, void* d_ws, size_t ws_size,
                              hipStream_t stream) {
    const float* ea   = (const float*)d_in[0];
    const float* ep   = (const float*)d_in[1];
    const float* en   = (const float*)d_in[2];
    const float* td   = (const float*)d_in[3];
    const int*   bidx = (const int*)d_in[4];
    float* out = (float*)d_out;

    const int B = in_sizes[4];                 // 16384 rows
    const int D = in_sizes[0] / B;             // 1024
    const int n_blocks = (B + ROWS_PER_BLOCK - 1) / ROWS_PER_BLOCK;

    float* partial = (float*)d_ws;             // n_blocks floats

    if (D == 1024) {
        st_loss_rows_1024<<<n_blocks, 256, 0, stream>>>(ea, ep, en, td, bidx,
                                                        partial, B);
    } else {
        st_loss_rows_gen<<<n_blocks, 256, 0, stream>>>(ea, ep, en, td, bidx,
                                                       partial, B, D);
    }
    st_loss_final<<<1, 256, 0, stream>>>(partial, n_blocks, out, 1.0f / (float)B);
}